// Round 6
// baseline (527.009 us; speedup 1.0000x reference)
//
#include <hip/hip_runtime.h>

// WaveRNN single-step forward, MI355X gfx950.
// Strategy: all GEMMs via mfma_f32_16x16x32_bf16 with hi/lo bf16 split
// (3-term: Ah*Bh + Ah*Bl + Al*Bh, fp32 accumulate) => ~fp32 accuracy.
// Workspace requirement: ~148.8 MB (aliased buffers, phase-ordered).
// ws_size guard: if harness workspace is smaller, do nothing (clean FAIL
// with poison-absmax instead of an OOB crash) -> diagnostic signal.

#define BM 64
#define BN 64
#define BK 32
#define LDST 40   // LDS row stride in ushorts (32 data + 8 pad = 80B, 16B-aligned, conflict-friendly)

typedef __attribute__((ext_vector_type(8))) short short8;
typedef __attribute__((ext_vector_type(8))) unsigned short ush8;
typedef __attribute__((ext_vector_type(4))) float f32x4;

__device__ __forceinline__ unsigned short f2bf(float f) {
    unsigned int u = __float_as_uint(f);
    u += 0x7fffu + ((u >> 16) & 1u);      // round-to-nearest-even
    return (unsigned short)(u >> 16);
}
__device__ __forceinline__ float bf2f(unsigned short h) {
    return __uint_as_float(((unsigned int)h) << 16);
}
__device__ __forceinline__ float sigm(float x)  { return 1.f / (1.f + __expf(-x)); }
__device__ __forceinline__ float tanh_f(float x){ return 1.f - 2.f / (__expf(2.f * x) + 1.f); }

struct EpiArgs {
    float* f32_out;               // EPI 0: X0 f32 / EPI 4: logits
    unsigned short* bf_h;         // split bf16 outputs (hi)
    unsigned short* bf_l;         // split bf16 outputs (lo)
    int out_stride;               // stride of bf16 out (512 or 576) / gh_out stride
    unsigned short* gh_out;       // EPI 1
    const unsigned short* gh_in;  // EPI 2 (includes b_hh)
    const float* hprev;           // EPI 2
    const float* xprev;           // EPI 2
    float* hn_out;                // EPI 2 -> d_out slice
    float* x_f32_out;             // EPI 2 (may be null)
};

// EPI: 0 = f32 + bf16-split out (input layer X0)
//      1 = bf16 out (gh = h@Whh.T + bhh)
//      2 = GRU gates fused (NSETS=3: r,z,n accumulators), writes h_new + X(+skip) split
//      3 = relu + bf16-split out (fc1, fc2)
//      4 = f32 out (fc3 logits)
template<int NSETS, int EPI>
__global__ __launch_bounds__(256)
void gemm_k(const unsigned short* __restrict__ Ah, const unsigned short* __restrict__ Al,
            const unsigned short* __restrict__ Wh, const unsigned short* __restrict__ Wl,
            const float* __restrict__ bias, int kpad, EpiArgs ea)
{
    __shared__ __align__(16) unsigned short lds[(2 + 2 * NSETS) * BM * LDST];
    unsigned short* As_h = lds;
    unsigned short* As_l = lds + BM * LDST;
    unsigned short* Bs   = lds + 2 * BM * LDST;   // per set: [Bh(64xLDST) | Bl(64xLDST)]

    const int t    = threadIdx.x;
    const int m0   = blockIdx.x * BM;
    const int n0   = blockIdx.y * BN;
    const int lane = t & 63;
    const int w    = t >> 6;
    const int wm   = (w >> 1) * 32;
    const int wn   = (w & 1) * 32;
    const int srow = t >> 2;          // 0..63: row staged by this thread
    const int skc  = (t & 3) * 8;     // k-chunk (8 bf16 = 16B)
    const int fr   = lane & 15;
    const int kg   = (lane >> 4) * 8; // fragment k-group (contiguous 8)

    f32x4 acc[NSETS][2][2] = {};

    for (int k0 = 0; k0 < kpad; k0 += BK) {
        {
            const size_t go = (size_t)(m0 + srow) * kpad + (k0 + skc);
            *(ush8*)(As_h + srow * LDST + skc) = *(const ush8*)(Ah + go);
            *(ush8*)(As_l + srow * LDST + skc) = *(const ush8*)(Al + go);
        }
        #pragma unroll
        for (int s = 0; s < NSETS; ++s) {
            const size_t go = (size_t)(s * 512 + n0 + srow) * kpad + (k0 + skc);
            unsigned short* bs = Bs + s * 2 * BM * LDST;
            *(ush8*)(bs + srow * LDST + skc)             = *(const ush8*)(Wh + go);
            *(ush8*)(bs + BM * LDST + srow * LDST + skc) = *(const ush8*)(Wl + go);
        }
        __syncthreads();

        short8 a_h[2], a_l[2];
        #pragma unroll
        for (int mi = 0; mi < 2; ++mi) {
            a_h[mi] = *(const short8*)(As_h + (wm + mi * 16 + fr) * LDST + kg);
            a_l[mi] = *(const short8*)(As_l + (wm + mi * 16 + fr) * LDST + kg);
        }
        #pragma unroll
        for (int s = 0; s < NSETS; ++s) {
            const unsigned short* bs = Bs + s * 2 * BM * LDST;
            #pragma unroll
            for (int ni = 0; ni < 2; ++ni) {
                short8 b_h = *(const short8*)(bs + (wn + ni * 16 + fr) * LDST + kg);
                short8 b_l = *(const short8*)(bs + BM * LDST + (wn + ni * 16 + fr) * LDST + kg);
                #pragma unroll
                for (int mi = 0; mi < 2; ++mi) {
                    acc[s][mi][ni] = __builtin_amdgcn_mfma_f32_16x16x32_bf16(a_h[mi], b_h, acc[s][mi][ni], 0, 0, 0);
                    acc[s][mi][ni] = __builtin_amdgcn_mfma_f32_16x16x32_bf16(a_h[mi], b_l, acc[s][mi][ni], 0, 0, 0);
                    acc[s][mi][ni] = __builtin_amdgcn_mfma_f32_16x16x32_bf16(a_l[mi], b_h, acc[s][mi][ni], 0, 0, 0);
                }
            }
        }
        __syncthreads();
    }

    // ---- epilogue ----
    #pragma unroll
    for (int mi = 0; mi < 2; ++mi)
    #pragma unroll
    for (int ni = 0; ni < 2; ++ni) {
        const int nn_ = n0 + wn + ni * 16 + fr;   // output column
        if constexpr (EPI == 2) {
            const float bir  = bias[nn_];
            const float biz  = bias[512 + nn_];
            const float bin_ = bias[1024 + nn_];
            #pragma unroll
            for (int v = 0; v < 4; ++v) {
                const int m = m0 + wm + mi * 16 + (lane >> 4) * 4 + v;
                const size_t g0 = (size_t)m * 1536;
                const size_t r0 = (size_t)m * 512;
                float ir  = acc[0][mi][ni][v] + bir;
                float iz  = acc[1][mi][ni][v] + biz;
                float inn = acc[2][mi][ni][v] + bin_;
                float hr = bf2f(ea.gh_in[g0 + nn_]);
                float hz = bf2f(ea.gh_in[g0 + 512 + nn_]);
                float hn = bf2f(ea.gh_in[g0 + 1024 + nn_]);
                float r  = sigm(ir + hr);
                float z  = sigm(iz + hz);
                float nv = tanh_f(inn + r * hn);
                float h  = ea.hprev[r0 + nn_];
                float hv = (1.f - z) * nv + z * h;
                ea.hn_out[r0 + nn_] = hv;
                float xv = ea.xprev[r0 + nn_] + hv;
                if (ea.x_f32_out) ea.x_f32_out[r0 + nn_] = xv;
                unsigned short xh = f2bf(xv);
                const size_t o = (size_t)m * ea.out_stride + nn_;
                ea.bf_h[o] = xh;
                ea.bf_l[o] = f2bf(xv - bf2f(xh));
            }
        } else {
            const float bv = bias[nn_];
            #pragma unroll
            for (int v = 0; v < 4; ++v) {
                const int m = m0 + wm + mi * 16 + (lane >> 4) * 4 + v;
                float val = acc[0][mi][ni][v] + bv;
                if constexpr (EPI == 0) {
                    const size_t o = (size_t)m * 512 + nn_;
                    ea.f32_out[o] = val;
                    unsigned short vh = f2bf(val);
                    ea.bf_h[o] = vh;
                    ea.bf_l[o] = f2bf(val - bf2f(vh));
                } else if constexpr (EPI == 1) {
                    ea.gh_out[(size_t)m * 1536 + nn_] = f2bf(val);
                } else if constexpr (EPI == 3) {
                    val = fmaxf(val, 0.f);
                    unsigned short vh = f2bf(val);
                    const size_t o = (size_t)m * ea.out_stride + nn_;
                    ea.bf_h[o] = vh;
                    ea.bf_l[o] = f2bf(val - bf2f(vh));
                } else {
                    ea.f32_out[(size_t)m * 512 + nn_] = val;
                }
            }
        }
    }
}

// ---- preprocessing kernels ----
struct SplitSeg { const float* src; unsigned short* dh; unsigned short* dl; int K; int Kpad; int total; };
struct SplitArgs { SplitSeg seg[10]; };

__global__ void k_split(SplitArgs a) {
    const SplitSeg s = a.seg[blockIdx.y];
    const int stride = gridDim.x * blockDim.x;
    for (int i = blockIdx.x * blockDim.x + threadIdx.x; i < s.total; i += stride) {
        float v;
        if (s.K == s.Kpad) v = s.src[i];
        else {
            int row = i / s.Kpad;
            int col = i - row * s.Kpad;
            v = (col < s.K) ? s.src[(size_t)row * s.K + col] : 0.f;
        }
        unsigned short h = f2bf(v);
        s.dh[i] = h;
        s.dl[i] = f2bf(v - bf2f(h));
    }
}

__global__ void k_build_c0(const float* __restrict__ x, const float* __restrict__ m,
                           const float* __restrict__ a1,
                           unsigned short* __restrict__ dh, unsigned short* __restrict__ dl) {
    int i = blockIdx.x * blockDim.x + threadIdx.x;   // 8192*128
    int row = i >> 7, col = i & 127;
    float v = 0.f;
    if (col == 0)       v = x[row];
    else if (col < 81)  v = m[row * 80 + (col - 1)];
    else if (col < 113) v = a1[row * 32 + (col - 81)];
    unsigned short h = f2bf(v);
    dh[i] = h;
    dl[i] = f2bf(v - bf2f(h));
}

__global__ void k_fill_tail(unsigned short* __restrict__ dh, unsigned short* __restrict__ dl,
                            const float* __restrict__ src) {
    int i = blockIdx.x * blockDim.x + threadIdx.x;   // 8192*64 (cols 512..576 of a 576-wide buffer)
    int row = i >> 6, col = i & 63;
    float v = (col < 32) ? src[row * 32 + col] : 0.f;
    size_t o = (size_t)row * 576 + 512 + col;
    unsigned short h = f2bf(v);
    dh[o] = h;
    dl[o] = f2bf(v - bf2f(h));
}

extern "C" void kernel_launch(void* const* d_in, const int* in_sizes, int n_in,
                              void* d_out, int out_size, void* d_ws, size_t ws_size,
                              hipStream_t stream)
{
    // ---- workspace layout (bytes), total 148,766,720 ----
    const size_t OFF_WI   = 0;          // 512x128   hi|lo (131072 each)
    const size_t OFF_W1IH = 262144;     // 1536x512  hi|lo (1572864 each)
    const size_t OFF_W1HH = 3407872;
    const size_t OFF_W2IH = 6553600;    // 1536x576  hi|lo (1769472 each)
    const size_t OFF_W2HH = 10092544;
    const size_t OFF_WFC1 = 13238272;   // 512x576   hi|lo (589824 each)
    const size_t OFF_WFC2 = 14417920;
    const size_t OFF_WFC3 = 15597568;   // 512x512   hi|lo (524288 each)
    const size_t OFF_H1H  = 16646144;   // 8192x512 bf16 x4 (h1h,h1l,h2h,h2l)
    const size_t OFF_H1L  = OFF_H1H + 8388608;
    const size_t OFF_H2H  = OFF_H1L + 8388608;
    const size_t OFF_H2L  = OFF_H2H + 8388608;
    const size_t OFF_C0H  = OFF_H1H + 33554432;   // 8192x128 bf16 x2
    const size_t OFF_C0L  = OFF_C0H + 2097152;
    const size_t OFF_X0H  = OFF_C0H + 4194304;    // 8192x512 bf16 x2
    const size_t OFF_X0L  = OFF_X0H + 8388608;
    const size_t OFF_X0F  = OFF_X0H + 16777216;   // 8192x512 f32
    const size_t OFF_GH   = OFF_X0F + 16777216;   // 8192x1536 bf16
    const size_t OFF_X1F  = OFF_GH  + 25165824;   // 8192x512 f32
    const size_t OFF_X1CH = OFF_X1F + 16777216;   // 8192x576 bf16 x2
    const size_t OFF_X1CL = OFF_X1CH + 9437184;
    // aliases (phase-ordered, see launch sequence):
    const size_t OFF_X2CH = OFF_H1H;              // after gh2: h1h/l + head of h2h are dead
    const size_t OFF_X2CL = OFF_H1H + 9437184;
    const size_t OFF_X3CH = OFF_C0H;              // after gi1: C0 + X0h/l dead
    const size_t OFF_X3CL = OFF_C0H + 9437184;
    const size_t OFF_X4H  = OFF_X0F;              // after gi1: X0 f32 dead
    const size_t OFF_X4L  = OFF_X0F + 8388608;
    const size_t WS_NEEDED = OFF_X1CL + 9437184;  // 148,766,720

    // Guard: if the harness workspace is too small, bail out cleanly instead
    // of writing OOB (which can wedge the GPU/container). Constant per-call.
    if (ws_size < WS_NEEDED) return;

    const float* m_t   = (const float*)d_in[0];
    const float* a1    = (const float*)d_in[1];
    const float* a2    = (const float*)d_in[2];
    const float* a3    = (const float*)d_in[3];
    const float* a4    = (const float*)d_in[4];
    const float* h1    = (const float*)d_in[5];
    const float* h2    = (const float*)d_in[6];
    const float* xin   = (const float*)d_in[7];
    const float* I_w   = (const float*)d_in[8];
    const float* I_b   = (const float*)d_in[9];
    const float* r1wih = (const float*)d_in[10];
    const float* r1whh = (const float*)d_in[11];
    const float* r1bih = (const float*)d_in[12];
    const float* r1bhh = (const float*)d_in[13];
    const float* r2wih = (const float*)d_in[14];
    const float* r2whh = (const float*)d_in[15];
    const float* r2bih = (const float*)d_in[16];
    const float* r2bhh = (const float*)d_in[17];
    const float* fc1w  = (const float*)d_in[18];
    const float* fc1b  = (const float*)d_in[19];
    const float* fc2w  = (const float*)d_in[20];
    const float* fc2b  = (const float*)d_in[21];
    const float* fc3w  = (const float*)d_in[22];
    const float* fc3b  = (const float*)d_in[23];
    float* out = (float*)d_out;

    char* ws = (char*)d_ws;
    auto U  = [&](size_t off) { return (unsigned short*)(ws + off); };
    auto Fp = [&](size_t off) { return (float*)(ws + off); };
    (void)in_sizes; (void)n_in; (void)out_size;

    // 1) split weights + h1/h2 into bf16 hi/lo (+K zero-pad)
    SplitArgs sa;
    sa.seg[0] = { I_w,   U(OFF_WI),   U(OFF_WI + 131072),    113, 128, 512 * 128 };
    sa.seg[1] = { r1wih, U(OFF_W1IH), U(OFF_W1IH + 1572864), 512, 512, 1536 * 512 };
    sa.seg[2] = { r1whh, U(OFF_W1HH), U(OFF_W1HH + 1572864), 512, 512, 1536 * 512 };
    sa.seg[3] = { r2wih, U(OFF_W2IH), U(OFF_W2IH + 1769472), 544, 576, 1536 * 576 };
    sa.seg[4] = { r2whh, U(OFF_W2HH), U(OFF_W2HH + 1572864), 512, 512, 1536 * 512 };
    sa.seg[5] = { fc1w,  U(OFF_WFC1), U(OFF_WFC1 + 589824),  544, 576, 512 * 576 };
    sa.seg[6] = { fc2w,  U(OFF_WFC2), U(OFF_WFC2 + 589824),  544, 576, 512 * 576 };
    sa.seg[7] = { fc3w,  U(OFF_WFC3), U(OFF_WFC3 + 524288),  512, 512, 512 * 512 };
    sa.seg[8] = { h1,    U(OFF_H1H),  U(OFF_H1L),            512, 512, 8192 * 512 };
    sa.seg[9] = { h2,    U(OFF_H2H),  U(OFF_H2L),            512, 512, 8192 * 512 };
    hipLaunchKernelGGL(k_split, dim3(512, 10), dim3(256), 0, stream, sa);

    // 2) C0 = [x | m_t | a1 | 0pad], split
    hipLaunchKernelGGL(k_build_c0, dim3(4096), dim3(256), 0, stream, xin, m_t, a1, U(OFF_C0H), U(OFF_C0L));
    // 3) X1cat tail = a2 (+pad)
    hipLaunchKernelGGL(k_fill_tail, dim3(2048), dim3(256), 0, stream, U(OFF_X1CH), U(OFF_X1CL), a2);

    EpiArgs ea{};

    // 4) G1: X0 = C0 @ I_w.T + I_b
    ea = EpiArgs{}; ea.f32_out = Fp(OFF_X0F); ea.bf_h = U(OFF_X0H); ea.bf_l = U(OFF_X0L); ea.out_stride = 512;
    hipLaunchKernelGGL((gemm_k<1, 0>), dim3(128, 8), dim3(256), 0, stream,
                       U(OFF_C0H), U(OFF_C0L), U(OFF_WI), U(OFF_WI + 131072), I_b, 128, ea);
    // 5) G2: gh1 = h1 @ r1_whh.T + r1_bhh  (bf16)
    ea = EpiArgs{}; ea.gh_out = U(OFF_GH); ea.out_stride = 1536;
    hipLaunchKernelGGL((gemm_k<1, 1>), dim3(128, 24), dim3(256), 0, stream,
                       U(OFF_H1H), U(OFF_H1L), U(OFF_W1HH), U(OFF_W1HH + 1572864), r1bhh, 512, ea);
    // 6) G3: gi1 + GRU1 gates -> h1n (out), X1 = X0 + h1n (f32 + split into X1cat)
    ea = EpiArgs{}; ea.gh_in = U(OFF_GH); ea.hprev = h1; ea.xprev = Fp(OFF_X0F);
    ea.hn_out = out + 4194304; ea.x_f32_out = Fp(OFF_X1F);
    ea.bf_h = U(OFF_X1CH); ea.bf_l = U(OFF_X1CL); ea.out_stride = 576;
    hipLaunchKernelGGL((gemm_k<3, 2>), dim3(128, 8), dim3(256), 0, stream,
                       U(OFF_X0H), U(OFF_X0L), U(OFF_W1IH), U(OFF_W1IH + 1572864), r1bih, 512, ea);
    // 7) G4: gh2 = h2 @ r2_whh.T + r2_bhh
    ea = EpiArgs{}; ea.gh_out = U(OFF_GH); ea.out_stride = 1536;
    hipLaunchKernelGGL((gemm_k<1, 1>), dim3(128, 24), dim3(256), 0, stream,
                       U(OFF_H2H), U(OFF_H2L), U(OFF_W2HH), U(OFF_W2HH + 1572864), r2bhh, 512, ea);
    // 8) X2cat tail = a3 (alias region dead only after gh2 -> placed here)
    hipLaunchKernelGGL(k_fill_tail, dim3(2048), dim3(256), 0, stream, U(OFF_X2CH), U(OFF_X2CL), a3);
    // 9) G5: gi2 + GRU2 gates -> h2n (out), X2 = X1 + h2n (split into X2cat)
    ea = EpiArgs{}; ea.gh_in = U(OFF_GH); ea.hprev = h2; ea.xprev = Fp(OFF_X1F);
    ea.hn_out = out + 8388608; ea.x_f32_out = nullptr;
    ea.bf_h = U(OFF_X2CH); ea.bf_l = U(OFF_X2CL); ea.out_stride = 576;
    hipLaunchKernelGGL((gemm_k<3, 2>), dim3(128, 8), dim3(256), 0, stream,
                       U(OFF_X1CH), U(OFF_X1CL), U(OFF_W2IH), U(OFF_W2IH + 1769472), r2bih, 576, ea);
    // 10) X3cat tail = a4
    hipLaunchKernelGGL(k_fill_tail, dim3(2048), dim3(256), 0, stream, U(OFF_X3CH), U(OFF_X3CL), a4);
    // 11) G6: fc1 relu
    ea = EpiArgs{}; ea.bf_h = U(OFF_X3CH); ea.bf_l = U(OFF_X3CL); ea.out_stride = 576;
    hipLaunchKernelGGL((gemm_k<1, 3>), dim3(128, 8), dim3(256), 0, stream,
                       U(OFF_X2CH), U(OFF_X2CL), U(OFF_WFC1), U(OFF_WFC1 + 589824), fc1b, 576, ea);
    // 12) G7: fc2 relu
    ea = EpiArgs{}; ea.bf_h = U(OFF_X4H); ea.bf_l = U(OFF_X4L); ea.out_stride = 512;
    hipLaunchKernelGGL((gemm_k<1, 3>), dim3(128, 8), dim3(256), 0, stream,
                       U(OFF_X3CH), U(OFF_X3CL), U(OFF_WFC2), U(OFF_WFC2 + 589824), fc2b, 576, ea);
    // 13) G8: logits = X4 @ fc3.T + b -> d_out[0:4194304]
    ea = EpiArgs{}; ea.f32_out = out;
    hipLaunchKernelGGL((gemm_k<1, 4>), dim3(128, 8), dim3(256), 0, stream,
                       U(OFF_X4H), U(OFF_X4L), U(OFF_WFC3), U(OFF_WFC3 + 524288), fc3b, 512, ea);
}

// Round 7
// 426.024 us; speedup vs baseline: 1.2370x; 1.2370x over previous
//
#include <hip/hip_runtime.h>

// WaveRNN single-step forward, MI355X gfx950.
// GEMMs: mfma_f32_16x16x32_bf16, 2-term hi/lo weight split (A_bf16*(Wh+Wl)),
// global_load_lds(16B) staging, double-buffered, 1 barrier per K-step.
// Workspace: 112,066,560 B (aliased, phase-ordered).

#define BK 32

typedef __attribute__((ext_vector_type(8))) short short8;
typedef __attribute__((ext_vector_type(4))) float f32x4;

__device__ __forceinline__ unsigned short f2bf(float f) {
    unsigned int u = __float_as_uint(f);
    u += 0x7fffu + ((u >> 16) & 1u);      // RNE
    return (unsigned short)(u >> 16);
}
__device__ __forceinline__ float bf2f(unsigned short h) {
    return __uint_as_float(((unsigned int)h) << 16);
}
__device__ __forceinline__ float sigm(float x)  { return 1.f / (1.f + __expf(-x)); }
__device__ __forceinline__ float tanh_f(float x){ return 1.f - 2.f / (__expf(2.f * x) + 1.f); }

__device__ __forceinline__ void gl16(const void* g, void* l) {
    __builtin_amdgcn_global_load_lds(
        (const __attribute__((address_space(1))) unsigned int*)g,
        (__attribute__((address_space(3))) unsigned int*)l, 16, 0, 0);
}

struct EpiArgs {
    float* f32_out;               // EPI 0 aux / EPI 4 logits
    unsigned short* bf_h;         // bf16 activation out
    int out_stride;
    unsigned short* gh_out;       // EPI 1
    const unsigned short* gh_in;  // EPI 2
    const float* hprev;           // EPI 2
    const float* xprev;           // EPI 2
    float* hn_out;                // EPI 2
    float* x_f32_out;             // EPI 2 (nullable)
};

// Tile: BM=64, BN=64 per set. 4 waves, wave = 64 rows x 16 cols (mi 0..3).
// LDS buffer (chunk-linear, 1KB chunks): Ah[64][32] | per set: Bh[64][32], Bl[64][32].
// EPI: 0 = f32 + bf16 out; 1 = bf16 gh out; 2 = fused GRU gates; 3 = relu bf16; 4 = f32 out
template<int NSETS, int EPI>
__global__ __launch_bounds__(256)
void gemm_k(const unsigned short* __restrict__ Ah,
            const unsigned short* __restrict__ Wh, const unsigned short* __restrict__ Wl,
            const float* __restrict__ bias, int kpad, EpiArgs ea)
{
    constexpr int NCHUNK = 4 + NSETS * 8;
    constexpr int BUFU   = NCHUNK * 512;          // ushorts per K-step buffer
    __shared__ __align__(16) unsigned short lds[2 * BUFU];

    const int t    = threadIdx.x;
    const int m0   = blockIdx.x * 64;
    const int n0   = blockIdx.y * 64;
    const int lane = t & 63;
    const int w    = t >> 6;
    const int rl   = lane >> 2;        // staging row within 16-row chunk
    const int cl   = (lane & 3) * 8;   // staging col (ushorts)
    const int fr   = lane & 15;
    const int kg   = (lane >> 4) * 8;

    f32x4 acc[NSETS][4] = {};
    const int NT = kpad >> 5;

    auto stage = [&](int buf, int k0) {
        unsigned short* dst = lds + buf * BUFU;
        // A chunk w: rows w*16 + rl
        gl16(Ah + (size_t)(m0 + w * 16 + rl) * kpad + (k0 + cl), dst + w * 512);
        #pragma unroll
        for (int j = 0; j < NSETS * 2; ++j) {           // j even: Bh, odd: Bl; s = j>>1
            const int s = j >> 1;
            const unsigned short* Wp = (j & 1) ? Wl : Wh;
            gl16(Wp + (size_t)(s * 512 + n0 + w * 16 + rl) * kpad + (k0 + cl),
                 dst + (4 + w + j * 4) * 512);
        }
    };

    stage(0, 0);
    __syncthreads();                                   // implicit vmcnt(0) drain

    int cur = 0;
    for (int tt = 0; tt < NT; ++tt) {
        if (tt + 1 < NT) stage(cur ^ 1, (tt + 1) * BK);  // prefetch next tile
        const unsigned short* Bb = lds + cur * BUFU;
        short8 a[4];
        #pragma unroll
        for (int mi = 0; mi < 4; ++mi)
            a[mi] = *(const short8*)(Bb + (mi * 16 + fr) * 32 + kg);
        #pragma unroll
        for (int s = 0; s < NSETS; ++s) {
            const unsigned short* bs = Bb + 2048 + s * 4096;
            short8 b_h = *(const short8*)(bs + (w * 16 + fr) * 32 + kg);
            short8 b_l = *(const short8*)(bs + 2048 + (w * 16 + fr) * 32 + kg);
            #pragma unroll
            for (int mi = 0; mi < 4; ++mi) {
                acc[s][mi] = __builtin_amdgcn_mfma_f32_16x16x32_bf16(a[mi], b_h, acc[s][mi], 0, 0, 0);
                acc[s][mi] = __builtin_amdgcn_mfma_f32_16x16x32_bf16(a[mi], b_l, acc[s][mi], 0, 0, 0);
            }
        }
        __syncthreads();                               // drains prefetch + read fences
        cur ^= 1;
    }

    // ---- epilogue: each thread owns column nn, 16 rows ----
    const int nn = n0 + w * 16 + fr;
    if constexpr (EPI == 2) {
        const float bir  = bias[nn];
        const float biz  = bias[512 + nn];
        const float bin_ = bias[1024 + nn];
        #pragma unroll
        for (int mi = 0; mi < 4; ++mi) {
            #pragma unroll
            for (int v = 0; v < 4; ++v) {
                const int m = m0 + mi * 16 + (lane >> 4) * 4 + v;
                const size_t g0 = (size_t)m * 1536;
                const size_t r0 = (size_t)m * 512;
                float ir  = acc[0][mi][v] + bir;
                float iz  = acc[1][mi][v] + biz;
                float inn = acc[2][mi][v] + bin_;
                float hr = bf2f(ea.gh_in[g0 + nn]);
                float hz = bf2f(ea.gh_in[g0 + 512 + nn]);
                float hn = bf2f(ea.gh_in[g0 + 1024 + nn]);
                float r  = sigm(ir + hr);
                float z  = sigm(iz + hz);
                float nv = tanh_f(inn + r * hn);
                float h  = ea.hprev[r0 + nn];
                float hv = (1.f - z) * nv + z * h;
                ea.hn_out[r0 + nn] = hv;
                float xv = ea.xprev[r0 + nn] + hv;
                if (ea.x_f32_out) ea.x_f32_out[r0 + nn] = xv;
                ea.bf_h[(size_t)m * ea.out_stride + nn] = f2bf(xv);
            }
        }
    } else {
        const float bv = bias[nn];
        #pragma unroll
        for (int mi = 0; mi < 4; ++mi) {
            #pragma unroll
            for (int v = 0; v < 4; ++v) {
                const int m = m0 + mi * 16 + (lane >> 4) * 4 + v;
                float val = acc[0][mi][v] + bv;
                if constexpr (EPI == 0) {
                    const size_t o = (size_t)m * 512 + nn;
                    ea.f32_out[o] = val;
                    ea.bf_h[o] = f2bf(val);
                } else if constexpr (EPI == 1) {
                    ea.gh_out[(size_t)m * 1536 + nn] = f2bf(val);
                } else if constexpr (EPI == 3) {
                    val = fmaxf(val, 0.f);
                    ea.bf_h[(size_t)m * ea.out_stride + nn] = f2bf(val);
                } else {
                    ea.f32_out[(size_t)m * 512 + nn] = val;
                }
            }
        }
    }
}

// ---- preprocessing ----
struct SplitSeg { const float* src; unsigned short* dh; unsigned short* dl; int K; int Kpad; int total; };
struct SplitArgs { SplitSeg seg[10]; };

__global__ void k_split(SplitArgs a) {
    const SplitSeg s = a.seg[blockIdx.y];
    const int stride = gridDim.x * blockDim.x;
    for (int i = blockIdx.x * blockDim.x + threadIdx.x; i < s.total; i += stride) {
        float v;
        if (s.K == s.Kpad) v = s.src[i];
        else {
            int row = i / s.Kpad;
            int col = i - row * s.Kpad;
            v = (col < s.K) ? s.src[(size_t)row * s.K + col] : 0.f;
        }
        unsigned short h = f2bf(v);
        s.dh[i] = h;
        if (s.dl) s.dl[i] = f2bf(v - bf2f(h));
    }
}

__global__ void k_build_c0(const float* __restrict__ x, const float* __restrict__ m,
                           const float* __restrict__ a1, unsigned short* __restrict__ dh) {
    int i = blockIdx.x * blockDim.x + threadIdx.x;   // 8192*128
    int row = i >> 7, col = i & 127;
    float v = 0.f;
    if (col == 0)       v = x[row];
    else if (col < 81)  v = m[row * 80 + (col - 1)];
    else if (col < 113) v = a1[row * 32 + (col - 81)];
    dh[i] = f2bf(v);
}

__global__ void k_fill_tail(unsigned short* __restrict__ dh, const float* __restrict__ src) {
    int i = blockIdx.x * blockDim.x + threadIdx.x;   // 8192*64 -> cols 512..575 of 576-wide
    int row = i >> 6, col = i & 63;
    float v = (col < 32) ? src[row * 32 + col] : 0.f;
    dh[(size_t)row * 576 + 512 + col] = f2bf(v);
}

extern "C" void kernel_launch(void* const* d_in, const int* in_sizes, int n_in,
                              void* d_out, int out_size, void* d_ws, size_t ws_size,
                              hipStream_t stream)
{
    // ---- workspace layout (bytes), total 112,066,560 ----
    const size_t OFF_WI   = 0;          // 512x128  hi|lo (131072 each)
    const size_t OFF_W1IH = 262144;     // 1536x512 hi|lo (1572864 each)
    const size_t OFF_W1HH = 3407872;
    const size_t OFF_W2IH = 6553600;    // 1536x576 hi|lo (1769472 each)
    const size_t OFF_W2HH = 10092544;   // 1536x512 hi|lo
    const size_t OFF_WFC1 = 13238272;   // 512x576 hi|lo (589824 each)
    const size_t OFF_WFC2 = 14417920;
    const size_t OFF_WFC3 = 15597568;   // 512x512 hi|lo (524288 each)
    const size_t OFF_H1H  = 16646144;   // 8192x512 bf16
    const size_t OFF_H2H  = 25034752;   // 8192x512 bf16
    const size_t OFF_C0H  = 33423360;   // 8192x128 bf16
    const size_t OFF_X0H  = 35520512;   // 8192x512 bf16
    const size_t OFF_X0F  = 43909120;   // 8192x512 f32
    const size_t OFF_GH   = 60686336;   // 8192x1536 bf16
    const size_t OFF_X1F  = 85852160;   // 8192x512 f32
    const size_t OFF_X1CH = 102629376;  // 8192x576 bf16  (end 112066560)
    // aliases (phase-ordered):
    const size_t OFF_X2CH = OFF_H1H;    // dead after G4 (gh2)
    const size_t OFF_X3CH = OFF_C0H;    // dead after G3 (gi1)
    const size_t OFF_X4H  = OFF_X0F;    // dead after G3
    const size_t WS_NEEDED = 112066560;
    if (ws_size < WS_NEEDED) return;    // clean-fail guard (constant per call)

    const float* m_t   = (const float*)d_in[0];
    const float* a1    = (const float*)d_in[1];
    const float* a2    = (const float*)d_in[2];
    const float* a3    = (const float*)d_in[3];
    const float* a4    = (const float*)d_in[4];
    const float* h1    = (const float*)d_in[5];
    const float* h2    = (const float*)d_in[6];
    const float* xin   = (const float*)d_in[7];
    const float* I_w   = (const float*)d_in[8];
    const float* I_b   = (const float*)d_in[9];
    const float* r1wih = (const float*)d_in[10];
    const float* r1whh = (const float*)d_in[11];
    const float* r1bih = (const float*)d_in[12];
    const float* r1bhh = (const float*)d_in[13];
    const float* r2wih = (const float*)d_in[14];
    const float* r2whh = (const float*)d_in[15];
    const float* r2bih = (const float*)d_in[16];
    const float* r2bhh = (const float*)d_in[17];
    const float* fc1w  = (const float*)d_in[18];
    const float* fc1b  = (const float*)d_in[19];
    const float* fc2w  = (const float*)d_in[20];
    const float* fc2b  = (const float*)d_in[21];
    const float* fc3w  = (const float*)d_in[22];
    const float* fc3b  = (const float*)d_in[23];
    float* out = (float*)d_out;

    char* ws = (char*)d_ws;
    auto U  = [&](size_t off) { return (unsigned short*)(ws + off); };
    auto Fp = [&](size_t off) { return (float*)(ws + off); };
    (void)in_sizes; (void)n_in; (void)out_size;

    // 1) split weights hi/lo; h1/h2 -> bf16 hi only
    SplitArgs sa;
    sa.seg[0] = { I_w,   U(OFF_WI),   U(OFF_WI + 131072),    113, 128, 512 * 128 };
    sa.seg[1] = { r1wih, U(OFF_W1IH), U(OFF_W1IH + 1572864), 512, 512, 1536 * 512 };
    sa.seg[2] = { r1whh, U(OFF_W1HH), U(OFF_W1HH + 1572864), 512, 512, 1536 * 512 };
    sa.seg[3] = { r2wih, U(OFF_W2IH), U(OFF_W2IH + 1769472), 544, 576, 1536 * 576 };
    sa.seg[4] = { r2whh, U(OFF_W2HH), U(OFF_W2HH + 1572864), 512, 512, 1536 * 512 };
    sa.seg[5] = { fc1w,  U(OFF_WFC1), U(OFF_WFC1 + 589824),  544, 576, 512 * 576 };
    sa.seg[6] = { fc2w,  U(OFF_WFC2), U(OFF_WFC2 + 589824),  544, 576, 512 * 576 };
    sa.seg[7] = { fc3w,  U(OFF_WFC3), U(OFF_WFC3 + 524288),  512, 512, 512 * 512 };
    sa.seg[8] = { h1,    U(OFF_H1H),  nullptr,               512, 512, 8192 * 512 };
    sa.seg[9] = { h2,    U(OFF_H2H),  nullptr,               512, 512, 8192 * 512 };
    hipLaunchKernelGGL(k_split, dim3(512, 10), dim3(256), 0, stream, sa);

    // 2) C0 = [x | m_t | a1 | pad]
    hipLaunchKernelGGL(k_build_c0, dim3(4096), dim3(256), 0, stream, xin, m_t, a1, U(OFF_C0H));
    // 3) X1cat tail = a2
    hipLaunchKernelGGL(k_fill_tail, dim3(2048), dim3(256), 0, stream, U(OFF_X1CH), a2);

    EpiArgs ea{};

    // 4) G1: X0 = C0 @ I_w.T + I_b
    ea = EpiArgs{}; ea.f32_out = Fp(OFF_X0F); ea.bf_h = U(OFF_X0H); ea.out_stride = 512;
    hipLaunchKernelGGL((gemm_k<1, 0>), dim3(128, 8), dim3(256), 0, stream,
                       U(OFF_C0H), U(OFF_WI), U(OFF_WI + 131072), I_b, 128, ea);
    // 5) G2: gh1 = h1 @ r1_whh.T + r1_bhh
    ea = EpiArgs{}; ea.gh_out = U(OFF_GH);
    hipLaunchKernelGGL((gemm_k<1, 1>), dim3(128, 24), dim3(256), 0, stream,
                       U(OFF_H1H), U(OFF_W1HH), U(OFF_W1HH + 1572864), r1bhh, 512, ea);
    // 6) G3: gi1 + GRU1 -> h1n, X1
    ea = EpiArgs{}; ea.gh_in = U(OFF_GH); ea.hprev = h1; ea.xprev = Fp(OFF_X0F);
    ea.hn_out = out + 4194304; ea.x_f32_out = Fp(OFF_X1F);
    ea.bf_h = U(OFF_X1CH); ea.out_stride = 576;
    hipLaunchKernelGGL((gemm_k<3, 2>), dim3(128, 8), dim3(256), 0, stream,
                       U(OFF_X0H), U(OFF_W1IH), U(OFF_W1IH + 1572864), r1bih, 512, ea);
    // 7) G4: gh2 = h2 @ r2_whh.T + r2_bhh
    ea = EpiArgs{}; ea.gh_out = U(OFF_GH);
    hipLaunchKernelGGL((gemm_k<1, 1>), dim3(128, 24), dim3(256), 0, stream,
                       U(OFF_H2H), U(OFF_W2HH), U(OFF_W2HH + 1572864), r2bhh, 512, ea);
    // 8) X2cat tail = a3 (region dead only after G4)
    hipLaunchKernelGGL(k_fill_tail, dim3(2048), dim3(256), 0, stream, U(OFF_X2CH), a3);
    // 9) G5: gi2 + GRU2 -> h2n, X2
    ea = EpiArgs{}; ea.gh_in = U(OFF_GH); ea.hprev = h2; ea.xprev = Fp(OFF_X1F);
    ea.hn_out = out + 8388608; ea.x_f32_out = nullptr;
    ea.bf_h = U(OFF_X2CH); ea.out_stride = 576;
    hipLaunchKernelGGL((gemm_k<3, 2>), dim3(128, 8), dim3(256), 0, stream,
                       U(OFF_X1CH), U(OFF_W2IH), U(OFF_W2IH + 1769472), r2bih, 576, ea);
    // 10) X3cat tail = a4
    hipLaunchKernelGGL(k_fill_tail, dim3(2048), dim3(256), 0, stream, U(OFF_X3CH), a4);
    // 11) G6: fc1 relu
    ea = EpiArgs{}; ea.bf_h = U(OFF_X3CH); ea.out_stride = 576;
    hipLaunchKernelGGL((gemm_k<1, 3>), dim3(128, 8), dim3(256), 0, stream,
                       U(OFF_X2CH), U(OFF_WFC1), U(OFF_WFC1 + 589824), fc1b, 576, ea);
    // 12) G7: fc2 relu
    ea = EpiArgs{}; ea.bf_h = U(OFF_X4H); ea.out_stride = 512;
    hipLaunchKernelGGL((gemm_k<1, 3>), dim3(128, 8), dim3(256), 0, stream,
                       U(OFF_X3CH), U(OFF_WFC2), U(OFF_WFC2 + 589824), fc2b, 576, ea);
    // 13) G8: logits -> d_out[0:4194304]
    ea = EpiArgs{}; ea.f32_out = out;
    hipLaunchKernelGGL((gemm_k<1, 4>), dim3(128, 8), dim3(256), 0, stream,
                       U(OFF_X4H), U(OFF_WFC3), U(OFF_WFC3 + 524288), fc3b, 512, ea);
}

// Round 9
// 337.044 us; speedup vs baseline: 1.5636x; 1.2640x over previous
//
#include <hip/hip_runtime.h>

// WaveRNN single-step forward, MI355X gfx950.
// All GEMMs plain bf16 (mfma_f32_16x16x32_bf16, fp32 accum).
// GRU cell fully fused: one kernel computes gi (from X) and gh (from h)
// with 6 accumulator sets and applies gates in the epilogue.
// global_load_lds(16B) staging, double-buffered, 1 barrier per K-step.
// Workspace: 107,085,824 B, no aliasing.

#define BK 32

typedef __attribute__((ext_vector_type(8))) short short8;
typedef __attribute__((ext_vector_type(4))) float f32x4;

__device__ __forceinline__ unsigned short f2bf(float f) {
    unsigned int u = __float_as_uint(f);
    u += 0x7fffu + ((u >> 16) & 1u);      // RNE
    return (unsigned short)(u >> 16);
}
__device__ __forceinline__ float bf2f(unsigned short h) {
    return __uint_as_float(((unsigned int)h) << 16);
}
__device__ __forceinline__ float sigm(float x)  { return 1.f / (1.f + __expf(-x)); }
__device__ __forceinline__ float tanh_f(float x){ return 1.f - 2.f / (__expf(2.f * x) + 1.f); }

__device__ __forceinline__ void gl16(const void* g, void* l) {
    __builtin_amdgcn_global_load_lds(
        (const __attribute__((address_space(1))) unsigned int*)g,
        (__attribute__((address_space(3))) unsigned int*)l, 16, 0, 0);
}

// ---------------- fused GRU cell kernel ----------------
// Tile 64x64 per gate-set; 4 waves, wave = 64 rows x 16 cols.
// LDS/buffer: A1[64][32] | A2[64][32] | 6 x B[64][32]  (32 KB), dbuf = 64 KB.
struct GruArgs {
    const float* hprev;       // [8192][512] f32 (d_in)
    const float* xprev;       // [8192][512] f32 (X before +h_new)
    float* hn_out;            // d_out slice
    float* x_f32_out;         // nullable
    unsigned short* x_bf_out; // bf16 X out
    int out_stride;           // 576
};

__global__ __launch_bounds__(256)
void gru_k(const unsigned short* __restrict__ A1, const unsigned short* __restrict__ A2,
           const unsigned short* __restrict__ Wih, const unsigned short* __restrict__ Whh,
           const float* __restrict__ bih, const float* __restrict__ bhh,
           int kpad, GruArgs g)
{
    constexpr int BUFU = 32 * 512;
    __shared__ __align__(16) unsigned short lds[2 * BUFU];
    const int t    = threadIdx.x;
    const int m0   = blockIdx.x * 64;
    const int n0   = blockIdx.y * 64;
    const int lane = t & 63;
    const int w    = t >> 6;
    const int rl   = lane >> 2;
    const int cl   = (lane & 3) * 8;
    const int fr   = lane & 15;
    const int kg   = (lane >> 4) * 8;

    f32x4 acc[6][4] = {};
    const int NT = kpad >> 5;

    auto stage = [&](int buf, int k0) {
        unsigned short* dst = lds + buf * BUFU;
        const size_t rowoff = (size_t)(m0 + w * 16 + rl) * kpad + (k0 + cl);
        gl16(A1 + rowoff, dst + w * 512);
        gl16(A2 + rowoff, dst + (4 + w) * 512);
        #pragma unroll
        for (int j = 0; j < 6; ++j) {
            const unsigned short* Wp = (j < 3) ? Wih : Whh;
            const int s = (j < 3) ? j : j - 3;
            gl16(Wp + (size_t)(s * 512 + n0 + w * 16 + rl) * kpad + (k0 + cl),
                 dst + (8 + j * 4 + w) * 512);
        }
    };

    stage(0, 0);
    __syncthreads();
    int cur = 0;
    for (int tt = 0; tt < NT; ++tt) {
        if (tt + 1 < NT) stage(cur ^ 1, (tt + 1) * BK);
        const unsigned short* Bb = lds + cur * BUFU;
        short8 a1[4], a2[4];
        #pragma unroll
        for (int mi = 0; mi < 4; ++mi) {
            a1[mi] = *(const short8*)(Bb + (mi * 16 + fr) * 32 + kg);
            a2[mi] = *(const short8*)(Bb + 2048 + (mi * 16 + fr) * 32 + kg);
        }
        #pragma unroll
        for (int j = 0; j < 6; ++j) {
            short8 b = *(const short8*)(Bb + 4096 + j * 2048 + (w * 16 + fr) * 32 + kg);
            #pragma unroll
            for (int mi = 0; mi < 4; ++mi)
                acc[j][mi] = __builtin_amdgcn_mfma_f32_16x16x32_bf16(
                    (j < 3) ? a1[mi] : a2[mi], b, acc[j][mi], 0, 0, 0);
        }
        __syncthreads();
        cur ^= 1;
    }

    const int nn = n0 + w * 16 + fr;
    const float bir = bih[nn], biz = bih[512 + nn], bin_ = bih[1024 + nn];
    const float bhr = bhh[nn], bhz = bhh[512 + nn], bhn = bhh[1024 + nn];
    #pragma unroll
    for (int mi = 0; mi < 4; ++mi)
    #pragma unroll
    for (int v = 0; v < 4; ++v) {
        const int m = m0 + mi * 16 + (lane >> 4) * 4 + v;
        const size_t r0 = (size_t)m * 512;
        float r  = sigm(acc[0][mi][v] + bir + acc[3][mi][v] + bhr);
        float z  = sigm(acc[1][mi][v] + biz + acc[4][mi][v] + bhz);
        float nv = tanh_f(acc[2][mi][v] + bin_ + r * (acc[5][mi][v] + bhn));
        float h  = g.hprev[r0 + nn];
        float hv = (1.f - z) * nv + z * h;
        g.hn_out[r0 + nn] = hv;
        float xv = g.xprev[r0 + nn] + hv;
        if (g.x_f32_out) g.x_f32_out[r0 + nn] = xv;
        g.x_bf_out[(size_t)m * g.out_stride + nn] = f2bf(xv);
    }
}

// ---------------- generic single-set GEMM ----------------
// EPI: 0 = f32 + bf16 out (I layer); 3 = relu bf16; 4 = f32 out (logits)
struct EpiArgs { float* f32_out; unsigned short* bf_h; int out_stride; };

template<int EPI>
__global__ __launch_bounds__(256)
void gemm_k(const unsigned short* __restrict__ A, const unsigned short* __restrict__ W,
            const float* __restrict__ bias, int kpad, EpiArgs ea)
{
    constexpr int BUFU = 8 * 512;
    __shared__ __align__(16) unsigned short lds[2 * BUFU];
    const int t    = threadIdx.x;
    const int m0   = blockIdx.x * 64;
    const int n0   = blockIdx.y * 64;
    const int lane = t & 63;
    const int w    = t >> 6;
    const int rl   = lane >> 2;
    const int cl   = (lane & 3) * 8;
    const int fr   = lane & 15;
    const int kg   = (lane >> 4) * 8;

    f32x4 acc[4] = {};
    const int NT = kpad >> 5;

    auto stage = [&](int buf, int k0) {
        unsigned short* dst = lds + buf * BUFU;
        gl16(A + (size_t)(m0 + w * 16 + rl) * kpad + (k0 + cl), dst + w * 512);
        gl16(W + (size_t)(n0 + w * 16 + rl) * kpad + (k0 + cl), dst + (4 + w) * 512);
    };

    stage(0, 0);
    __syncthreads();
    int cur = 0;
    for (int tt = 0; tt < NT; ++tt) {
        if (tt + 1 < NT) stage(cur ^ 1, (tt + 1) * BK);
        const unsigned short* Bb = lds + cur * BUFU;
        short8 b = *(const short8*)(Bb + 2048 + (w * 16 + fr) * 32 + kg);
        #pragma unroll
        for (int mi = 0; mi < 4; ++mi) {
            short8 a = *(const short8*)(Bb + (mi * 16 + fr) * 32 + kg);
            acc[mi] = __builtin_amdgcn_mfma_f32_16x16x32_bf16(a, b, acc[mi], 0, 0, 0);
        }
        __syncthreads();
        cur ^= 1;
    }

    const int nn = n0 + w * 16 + fr;
    const float bv = bias[nn];
    #pragma unroll
    for (int mi = 0; mi < 4; ++mi)
    #pragma unroll
    for (int v = 0; v < 4; ++v) {
        const int m = m0 + mi * 16 + (lane >> 4) * 4 + v;
        float val = acc[mi][v] + bv;
        if constexpr (EPI == 0) {
            const size_t o = (size_t)m * 512 + nn;
            ea.f32_out[o] = val;
            ea.bf_h[o] = f2bf(val);
        } else if constexpr (EPI == 3) {
            val = fmaxf(val, 0.f);
            ea.bf_h[(size_t)m * ea.out_stride + nn] = f2bf(val);
        } else {
            ea.f32_out[(size_t)m * 512 + nn] = val;
        }
    }
}

// ---------------- preprocessing ----------------
struct SplitSeg { const float* src; unsigned short* dh; int K; int Kpad; int total; };
struct SplitArgs { SplitSeg seg[10]; };

__global__ void k_split(SplitArgs a) {
    const SplitSeg s = a.seg[blockIdx.y];
    const int stride = gridDim.x * blockDim.x;
    for (int i = blockIdx.x * blockDim.x + threadIdx.x; i < s.total; i += stride) {
        float v;
        if (s.K == s.Kpad) v = s.src[i];
        else {
            int row = i / s.Kpad;
            int col = i - row * s.Kpad;
            v = (col < s.K) ? s.src[(size_t)row * s.K + col] : 0.f;
        }
        s.dh[i] = f2bf(v);
    }
}

__global__ void k_build_c0(const float* __restrict__ x, const float* __restrict__ m,
                           const float* __restrict__ a1, unsigned short* __restrict__ dh) {
    int i = blockIdx.x * blockDim.x + threadIdx.x;   // 8192*128
    int row = i >> 7, col = i & 127;
    float v = 0.f;
    if (col == 0)       v = x[row];
    else if (col < 81)  v = m[row * 80 + (col - 1)];
    else if (col < 113) v = a1[row * 32 + (col - 81)];
    dh[i] = f2bf(v);
}

__global__ void k_fill_tail(unsigned short* __restrict__ dh, const float* __restrict__ src) {
    int i = blockIdx.x * blockDim.x + threadIdx.x;   // 8192*64 -> cols 512..575 of 576-wide
    int row = i >> 6, col = i & 63;
    float v = (col < 32) ? src[row * 32 + col] : 0.f;
    dh[(size_t)row * 576 + 512 + col] = f2bf(v);
}

extern "C" void kernel_launch(void* const* d_in, const int* in_sizes, int n_in,
                              void* d_out, int out_size, void* d_ws, size_t ws_size,
                              hipStream_t stream)
{
    // ---- workspace layout (bytes), total 107,085,824, no aliasing ----
    const size_t OFF_WI   = 0;           // 512x128  bf16
    const size_t OFF_W1IH = 131072;      // 1536x512 bf16
    const size_t OFF_W1HH = 1703936;     // 1536x512 bf16
    const size_t OFF_W2IH = 3276800;     // 1536x576 bf16
    const size_t OFF_W2HH = 5046272;     // 1536x576 bf16 (K 512->576 zero-pad)
    const size_t OFF_WFC1 = 6815744;     // 512x576 bf16
    const size_t OFF_WFC2 = 7405568;     // 512x576 bf16
    const size_t OFF_WFC3 = 7995392;     // 512x512 bf16
    const size_t OFF_H1   = 8519680;     // 8192x512 bf16
    const size_t OFF_H2   = 16908288;    // 8192x576 bf16 (zero-pad)
    const size_t OFF_C0   = 26345472;    // 8192x128 bf16
    const size_t OFF_X0H  = 28442624;    // 8192x512 bf16
    const size_t OFF_X0F  = 36831232;    // 8192x512 f32
    const size_t OFF_X1F  = 53608448;    // 8192x512 f32
    const size_t OFF_X1C  = 70385664;    // 8192x576 bf16
    const size_t OFF_X2C  = 79822848;    // 8192x576 bf16
    const size_t OFF_X3C  = 89260032;    // 8192x576 bf16
    const size_t OFF_X4   = 98697216;    // 8192x512 bf16
    const size_t WS_NEEDED = 107085824;
    if (ws_size < WS_NEEDED) return;     // clean-fail guard (constant per call)

    const float* m_t   = (const float*)d_in[0];
    const float* a1    = (const float*)d_in[1];
    const float* a2    = (const float*)d_in[2];
    const float* a3    = (const float*)d_in[3];
    const float* a4    = (const float*)d_in[4];
    const float* h1    = (const float*)d_in[5];
    const float* h2    = (const float*)d_in[6];
    const float* xin   = (const float*)d_in[7];
    const float* I_w   = (const float*)d_in[8];
    const float* I_b   = (const float*)d_in[9];
    const float* r1wih = (const float*)d_in[10];
    const float* r1whh = (const float*)d_in[11];
    const float* r1bih = (const float*)d_in[12];
    const float* r1bhh = (const float*)d_in[13];
    const float* r2wih = (const float*)d_in[14];
    const float* r2whh = (const float*)d_in[15];
    const float* r2bih = (const float*)d_in[16];
    const float* r2bhh = (const float*)d_in[17];
    const float* fc1w  = (const float*)d_in[18];
    const float* fc1b  = (const float*)d_in[19];
    const float* fc2w  = (const float*)d_in[20];
    const float* fc2b  = (const float*)d_in[21];
    const float* fc3w  = (const float*)d_in[22];
    const float* fc3b  = (const float*)d_in[23];
    float* out = (float*)d_out;

    char* ws = (char*)d_ws;
    auto U  = [&](size_t off) { return (unsigned short*)(ws + off); };
    auto Fp = [&](size_t off) { return (float*)(ws + off); };
    (void)in_sizes; (void)n_in; (void)out_size;

    // 1) cast/pad weights + h1/h2 to bf16
    SplitArgs sa;
    sa.seg[0] = { I_w,   U(OFF_WI),   113, 128, 512 * 128 };
    sa.seg[1] = { r1wih, U(OFF_W1IH), 512, 512, 1536 * 512 };
    sa.seg[2] = { r1whh, U(OFF_W1HH), 512, 512, 1536 * 512 };
    sa.seg[3] = { r2wih, U(OFF_W2IH), 544, 576, 1536 * 576 };
    sa.seg[4] = { r2whh, U(OFF_W2HH), 512, 576, 1536 * 576 };
    sa.seg[5] = { fc1w,  U(OFF_WFC1), 544, 576, 512 * 576 };
    sa.seg[6] = { fc2w,  U(OFF_WFC2), 544, 576, 512 * 576 };
    sa.seg[7] = { fc3w,  U(OFF_WFC3), 512, 512, 512 * 512 };
    sa.seg[8] = { h1,    U(OFF_H1),   512, 512, 8192 * 512 };
    sa.seg[9] = { h2,    U(OFF_H2),   512, 576, 8192 * 576 };
    hipLaunchKernelGGL(k_split, dim3(512, 10), dim3(256), 0, stream, sa);

    // 2) C0 = [x | m_t | a1 | pad];  aux tails of X1C/X2C/X3C
    hipLaunchKernelGGL(k_build_c0, dim3(4096), dim3(256), 0, stream, xin, m_t, a1, U(OFF_C0));
    hipLaunchKernelGGL(k_fill_tail, dim3(2048), dim3(256), 0, stream, U(OFF_X1C), a2);
    hipLaunchKernelGGL(k_fill_tail, dim3(2048), dim3(256), 0, stream, U(OFF_X2C), a3);
    hipLaunchKernelGGL(k_fill_tail, dim3(2048), dim3(256), 0, stream, U(OFF_X3C), a4);

    // 3) G1: X0 = C0 @ I_w.T + I_b   (f32 + bf16)
    EpiArgs ea{};
    ea.f32_out = Fp(OFF_X0F); ea.bf_h = U(OFF_X0H); ea.out_stride = 512;
    hipLaunchKernelGGL((gemm_k<0>), dim3(128, 8), dim3(256), 0, stream,
                       U(OFF_C0), U(OFF_WI), I_b, 128, ea);

    // 4) GRU1 fused -> h1n (out), X1 (f32 + bf16 into X1C)
    GruArgs g{};
    g.hprev = h1; g.xprev = Fp(OFF_X0F);
    g.hn_out = out + 4194304; g.x_f32_out = Fp(OFF_X1F);
    g.x_bf_out = U(OFF_X1C); g.out_stride = 576;
    hipLaunchKernelGGL(gru_k, dim3(128, 8), dim3(256), 0, stream,
                       U(OFF_X0H), U(OFF_H1), U(OFF_W1IH), U(OFF_W1HH), r1bih, r1bhh, 512, g);

    // 5) GRU2 fused -> h2n (out), X2 (bf16 into X2C)
    g = GruArgs{};
    g.hprev = h2; g.xprev = Fp(OFF_X1F);
    g.hn_out = out + 8388608; g.x_f32_out = nullptr;
    g.x_bf_out = U(OFF_X2C); g.out_stride = 576;
    hipLaunchKernelGGL(gru_k, dim3(128, 8), dim3(256), 0, stream,
                       U(OFF_X1C), U(OFF_H2), U(OFF_W2IH), U(OFF_W2HH), r2bih, r2bhh, 576, g);

    // 6) fc1 relu -> X3C
    ea = EpiArgs{}; ea.bf_h = U(OFF_X3C); ea.out_stride = 576;
    hipLaunchKernelGGL((gemm_k<3>), dim3(128, 8), dim3(256), 0, stream,
                       U(OFF_X2C), U(OFF_WFC1), fc1b, 576, ea);
    // 7) fc2 relu -> X4
    ea = EpiArgs{}; ea.bf_h = U(OFF_X4); ea.out_stride = 512;
    hipLaunchKernelGGL((gemm_k<3>), dim3(128, 8), dim3(256), 0, stream,
                       U(OFF_X3C), U(OFF_WFC2), fc2b, 576, ea);
    // 8) fc3 logits -> d_out[0:4194304]
    ea = EpiArgs{}; ea.f32_out = out;
    hipLaunchKernelGGL((gemm_k<4>), dim3(128, 8), dim3(256), 0, stream,
                       U(OFF_X4), U(OFF_WFC3), fc3b, 512, ea);
}

// Round 11
// 326.698 us; speedup vs baseline: 1.6131x; 1.0317x over previous
//
#include <hip/hip_runtime.h>

// WaveRNN single-step forward, MI355X gfx950.
// bf16 MFMA GEMMs. GRU fused kernel: 8 waves, gate-specialized
// (waves 0-3 gi from X, 4-7 gh from h), BM=128/BN=64, 80KB dynamic LDS dbuf,
// cross-wave LDS combine in epilogue. Workspace: 107,085,824 B.

#define BK 32

typedef __attribute__((ext_vector_type(8))) short short8;
typedef __attribute__((ext_vector_type(4))) float f32x4;
typedef __attribute__((ext_vector_type(8))) unsigned short ush8;

__device__ __forceinline__ unsigned short f2bf(float f) {
    unsigned int u = __float_as_uint(f);
    u += 0x7fffu + ((u >> 16) & 1u);      // RNE
    return (unsigned short)(u >> 16);
}
__device__ __forceinline__ float bf2f(unsigned short h) {
    return __uint_as_float(((unsigned int)h) << 16);
}
__device__ __forceinline__ float sigm(float x)  { return 1.f / (1.f + __expf(-x)); }
__device__ __forceinline__ float tanh_f(float x){ return 1.f - 2.f / (__expf(2.f * x) + 1.f); }

__device__ __forceinline__ void gl16(const void* g, void* l) {
    __builtin_amdgcn_global_load_lds(
        (const __attribute__((address_space(1))) unsigned int*)g,
        (__attribute__((address_space(3))) unsigned int*)l, 16, 0, 0);
}

// ---------------- fused GRU cell kernel ----------------
// 512 thr / 8 waves. Block: 128 rows x 64 cols x 3 gates (gi+gh).
// LDS buffer (40KB): A1[128][32] | A2[128][32] | B[6][64][32]; dbuf 80KB dynamic.
// Staging: 2560 16B-units/buffer, 5 gl16 per thread, unit u = k*512 + w*64 + lane.
struct GruArgs {
    const float* hprev;       // [8192][512] f32
    const float* xprev;       // [8192][512] f32
    float* hn_out;            // d_out slice
    float* x_f32_out;         // nullable
    unsigned short* x_bf_out; // bf16 X out
    int out_stride;           // 576
};

__global__ __launch_bounds__(512)
void gru_k(const unsigned short* __restrict__ A1, const unsigned short* __restrict__ A2,
           const unsigned short* __restrict__ Wih, const unsigned short* __restrict__ Whh,
           const float* __restrict__ bih, const float* __restrict__ bhh,
           int kpad, GruArgs g)
{
    extern __shared__ __align__(16) unsigned short lds[];
    constexpr int BUFU = 20480;               // ushorts per buffer (40KB)
    const int t    = threadIdx.x;
    const int w    = t >> 6;
    const int lane = t & 63;
    const int isgi = (w < 4);
    const int ww   = w & 3;
    const int mh   = ww >> 1;                 // 0/1: 64-row half
    const int nh   = ww & 1;                  // 0/1: 32-col half
    const int m0   = blockIdx.x * 128;
    const int n0   = blockIdx.y * 64;
    const int fr   = lane & 15;
    const int kg   = (lane >> 4) * 8;
    const int NT   = kpad >> 5;

    f32x4 acc[3][4][2] = {};

    auto stage = [&](int buf, int k0) {
        unsigned short* dst = lds + buf * BUFU;
        #pragma unroll
        for (int k = 0; k < 5; ++k) {
            const int u = k * 512 + w * 64 + lane;
            const unsigned short* src;
            if (u < 512) {
                src = A1 + (size_t)(m0 + (u >> 2)) * kpad + k0 + (u & 3) * 8;
            } else if (u < 1024) {
                src = A2 + (size_t)(m0 + ((u - 512) >> 2)) * kpad + k0 + (u & 3) * 8;
            } else {
                const int v = u - 1024;
                const int p = v >> 8;                       // panel 0..5
                const int r = (v & 255) >> 2;               // row 0..63
                const unsigned short* Wp = (p < 3) ? Wih : Whh;
                const int s = (p < 3) ? p : p - 3;
                src = Wp + (size_t)(s * 512 + n0 + r) * kpad + k0 + (u & 3) * 8;
            }
            gl16(src, dst + (size_t)(k * 512 + w * 64) * 8);   // HW adds lane*16B
        }
    };

    stage(0, 0);
    __syncthreads();
    int cur = 0;
    for (int tt = 0; tt < NT; ++tt) {
        if (tt + 1 < NT) stage(cur ^ 1, (tt + 1) * BK);
        const unsigned short* B0 = lds + cur * BUFU;
        const unsigned short* Ab = B0 + (isgi ? 0 : 4096);
        short8 a[4];
        #pragma unroll
        for (int mi = 0; mi < 4; ++mi)
            a[mi] = *(const short8*)(Ab + (mh * 64 + mi * 16 + fr) * 32 + kg);
        #pragma unroll
        for (int s = 0; s < 3; ++s) {
            const unsigned short* Bp = B0 + 8192 + (isgi ? s : s + 3) * 2048;
            #pragma unroll
            for (int ni = 0; ni < 2; ++ni) {
                short8 b = *(const short8*)(Bp + (nh * 32 + ni * 16 + fr) * 32 + kg);
                #pragma unroll
                for (int mi = 0; mi < 4; ++mi)
                    acc[s][mi][ni] = __builtin_amdgcn_mfma_f32_16x16x32_bf16(a[mi], b, acc[s][mi][ni], 0, 0, 0);
            }
        }
        __syncthreads();
        cur ^= 1;
    }

    // ---- epilogue: gh waves hand partials to gi waves via LDS ----
    float* xf = (float*)lds;
    // f32 slot: set_region*8192 + ww*2048 + (mi*2+ni)*256 + lane*4
    if (!isgi) {
        #pragma unroll
        for (int s = 0; s < 2; ++s)
        #pragma unroll
        for (int mi = 0; mi < 4; ++mi)
        #pragma unroll
        for (int ni = 0; ni < 2; ++ni)
            *(f32x4*)(xf + s * 8192 + ww * 2048 + (mi * 2 + ni) * 256 + lane * 4) = acc[s][mi][ni];
    }
    __syncthreads();
    if (isgi) {
        #pragma unroll
        for (int mi = 0; mi < 4; ++mi)
        #pragma unroll
        for (int ni = 0; ni < 2; ++ni) {
            const int nn = n0 + nh * 32 + ni * 16 + fr;
            const float bir = bih[nn] + bhh[nn];
            const float biz = bih[512 + nn] + bhh[512 + nn];
            f32x4 ghr = *(const f32x4*)(xf + ww * 2048 + (mi * 2 + ni) * 256 + lane * 4);
            f32x4 ghz = *(const f32x4*)(xf + 8192 + ww * 2048 + (mi * 2 + ni) * 256 + lane * 4);
            #pragma unroll
            for (int v = 0; v < 4; ++v) {
                acc[0][mi][ni][v] = sigm(acc[0][mi][ni][v] + ghr[v] + bir);
                acc[1][mi][ni][v] = sigm(acc[1][mi][ni][v] + ghz[v] + biz);
            }
        }
    }
    __syncthreads();
    if (!isgi) {
        #pragma unroll
        for (int mi = 0; mi < 4; ++mi)
        #pragma unroll
        for (int ni = 0; ni < 2; ++ni)
            *(f32x4*)(xf + ww * 2048 + (mi * 2 + ni) * 256 + lane * 4) = acc[2][mi][ni];
    }
    __syncthreads();
    if (isgi) {
        #pragma unroll
        for (int mi = 0; mi < 4; ++mi)
        #pragma unroll
        for (int ni = 0; ni < 2; ++ni) {
            const int nn = n0 + nh * 32 + ni * 16 + fr;
            const float bin_ = bih[1024 + nn];
            const float bhn  = bhh[1024 + nn];
            f32x4 ghn = *(const f32x4*)(xf + ww * 2048 + (mi * 2 + ni) * 256 + lane * 4);
            #pragma unroll
            for (int v = 0; v < 4; ++v) {
                const int m = m0 + mh * 64 + mi * 16 + (lane >> 4) * 4 + v;
                const size_t r0 = (size_t)m * 512;
                float r  = acc[0][mi][ni][v];
                float z  = acc[1][mi][ni][v];
                float nv = tanh_f(acc[2][mi][ni][v] + bin_ + r * (ghn[v] + bhn));
                float h  = g.hprev[r0 + nn];
                float hv = (1.f - z) * nv + z * h;
                g.hn_out[r0 + nn] = hv;
                float xv = g.xprev[r0 + nn] + hv;
                if (g.x_f32_out) g.x_f32_out[r0 + nn] = xv;
                g.x_bf_out[(size_t)m * g.out_stride + nn] = f2bf(xv);
            }
        }
    }
}

// ---------------- generic single-set GEMM (unchanged from r9) ----------------
// EPI: 0 = f32 + bf16 out (I layer); 3 = relu bf16; 4 = f32 out (logits)
struct EpiArgs { float* f32_out; unsigned short* bf_h; int out_stride; };

template<int EPI>
__global__ __launch_bounds__(256)
void gemm_k(const unsigned short* __restrict__ A, const unsigned short* __restrict__ W,
            const float* __restrict__ bias, int kpad, EpiArgs ea)
{
    constexpr int BUFU = 8 * 512;
    __shared__ __align__(16) unsigned short lds[2 * BUFU];
    const int t    = threadIdx.x;
    const int m0   = blockIdx.x * 64;
    const int n0   = blockIdx.y * 64;
    const int lane = t & 63;
    const int w    = t >> 6;
    const int rl   = lane >> 2;
    const int cl   = (lane & 3) * 8;
    const int fr   = lane & 15;
    const int kg   = (lane >> 4) * 8;

    f32x4 acc[4] = {};
    const int NT = kpad >> 5;

    auto stage = [&](int buf, int k0) {
        unsigned short* dst = lds + buf * BUFU;
        gl16(A + (size_t)(m0 + w * 16 + rl) * kpad + (k0 + cl), dst + w * 512);
        gl16(W + (size_t)(n0 + w * 16 + rl) * kpad + (k0 + cl), dst + (4 + w) * 512);
    };

    stage(0, 0);
    __syncthreads();
    int cur = 0;
    for (int tt = 0; tt < NT; ++tt) {
        if (tt + 1 < NT) stage(cur ^ 1, (tt + 1) * BK);
        const unsigned short* Bb = lds + cur * BUFU;
        short8 b = *(const short8*)(Bb + 2048 + (w * 16 + fr) * 32 + kg);
        #pragma unroll
        for (int mi = 0; mi < 4; ++mi) {
            short8 a = *(const short8*)(Bb + (mi * 16 + fr) * 32 + kg);
            acc[mi] = __builtin_amdgcn_mfma_f32_16x16x32_bf16(a, b, acc[mi], 0, 0, 0);
        }
        __syncthreads();
        cur ^= 1;
    }

    const int nn = n0 + w * 16 + fr;
    const float bv = bias[nn];
    #pragma unroll
    for (int mi = 0; mi < 4; ++mi)
    #pragma unroll
    for (int v = 0; v < 4; ++v) {
        const int m = m0 + mi * 16 + (lane >> 4) * 4 + v;
        float val = acc[mi][v] + bv;
        if constexpr (EPI == 0) {
            const size_t o = (size_t)m * 512 + nn;
            ea.f32_out[o] = val;
            ea.bf_h[o] = f2bf(val);
        } else if constexpr (EPI == 3) {
            val = fmaxf(val, 0.f);
            ea.bf_h[(size_t)m * ea.out_stride + nn] = f2bf(val);
        } else {
            ea.f32_out[(size_t)m * 512 + nn] = val;
        }
    }
}

// ---------------- preprocessing ----------------
struct SplitSeg { const float* src; unsigned short* dh; int K; int Kpad; int total; };
struct SplitArgs { SplitSeg seg[10]; };

__global__ void k_split(SplitArgs a) {
    const SplitSeg s = a.seg[blockIdx.y];
    const int stride = gridDim.x * blockDim.x;
    const int tid0 = blockIdx.x * blockDim.x + threadIdx.x;
    if (s.K == s.Kpad) {                       // vectorized cast (totals % 8 == 0)
        const int n8 = s.total >> 3;
        const float4* src4 = (const float4*)s.src;
        ush8* dst8 = (ush8*)s.dh;
        for (int i = tid0; i < n8; i += stride) {
            float4 f0 = src4[i * 2];
            float4 f1 = src4[i * 2 + 1];
            ush8 o;
            o[0] = f2bf(f0.x); o[1] = f2bf(f0.y); o[2] = f2bf(f0.z); o[3] = f2bf(f0.w);
            o[4] = f2bf(f1.x); o[5] = f2bf(f1.y); o[6] = f2bf(f1.z); o[7] = f2bf(f1.w);
            dst8[i] = o;
        }
    } else {
        for (int i = tid0; i < s.total; i += stride) {
            int row = i / s.Kpad;
            int col = i - row * s.Kpad;
            float v = (col < s.K) ? s.src[(size_t)row * s.K + col] : 0.f;
            s.dh[i] = f2bf(v);
        }
    }
}

__global__ void k_build_c0(const float* __restrict__ x, const float* __restrict__ m,
                           const float* __restrict__ a1, unsigned short* __restrict__ dh) {
    int i = blockIdx.x * blockDim.x + threadIdx.x;   // 8192*128
    int row = i >> 7, col = i & 127;
    float v = 0.f;
    if (col == 0)       v = x[row];
    else if (col < 81)  v = m[row * 80 + (col - 1)];
    else if (col < 113) v = a1[row * 32 + (col - 81)];
    dh[i] = f2bf(v);
}

__global__ void k_fill_tail(unsigned short* __restrict__ dh, const float* __restrict__ src) {
    int i = blockIdx.x * blockDim.x + threadIdx.x;   // 8192*64 -> cols 512..575 of 576-wide
    int row = i >> 6, col = i & 63;
    float v = (col < 32) ? src[row * 32 + col] : 0.f;
    dh[(size_t)row * 576 + 512 + col] = f2bf(v);
}

extern "C" void kernel_launch(void* const* d_in, const int* in_sizes, int n_in,
                              void* d_out, int out_size, void* d_ws, size_t ws_size,
                              hipStream_t stream)
{
    // ---- workspace layout (bytes), total 107,085,824, no aliasing ----
    const size_t OFF_WI   = 0;           // 512x128  bf16
    const size_t OFF_W1IH = 131072;      // 1536x512 bf16
    const size_t OFF_W1HH = 1703936;     // 1536x512 bf16
    const size_t OFF_W2IH = 3276800;     // 1536x576 bf16
    const size_t OFF_W2HH = 5046272;     // 1536x576 bf16 (K 512->576 zero-pad)
    const size_t OFF_WFC1 = 6815744;     // 512x576 bf16
    const size_t OFF_WFC2 = 7405568;     // 512x576 bf16
    const size_t OFF_WFC3 = 7995392;     // 512x512 bf16
    const size_t OFF_H1   = 8519680;     // 8192x512 bf16
    const size_t OFF_H2   = 16908288;    // 8192x576 bf16 (zero-pad)
    const size_t OFF_C0   = 26345472;    // 8192x128 bf16
    const size_t OFF_X0H  = 28442624;    // 8192x512 bf16
    const size_t OFF_X0F  = 36831232;    // 8192x512 f32
    const size_t OFF_X1F  = 53608448;    // 8192x512 f32
    const size_t OFF_X1C  = 70385664;    // 8192x576 bf16
    const size_t OFF_X2C  = 79822848;    // 8192x576 bf16
    const size_t OFF_X3C  = 89260032;    // 8192x576 bf16
    const size_t OFF_X4   = 98697216;    // 8192x512 bf16
    const size_t WS_NEEDED = 107085824;
    if (ws_size < WS_NEEDED) return;     // clean-fail guard (constant per call)

    const float* m_t   = (const float*)d_in[0];
    const float* a1    = (const float*)d_in[1];
    const float* a2    = (const float*)d_in[2];
    const float* a3    = (const float*)d_in[3];
    const float* a4    = (const float*)d_in[4];
    const float* h1    = (const float*)d_in[5];
    const float* h2    = (const float*)d_in[6];
    const float* xin   = (const float*)d_in[7];
    const float* I_w   = (const float*)d_in[8];
    const float* I_b   = (const float*)d_in[9];
    const float* r1wih = (const float*)d_in[10];
    const float* r1whh = (const float*)d_in[11];
    const float* r1bih = (const float*)d_in[12];
    const float* r1bhh = (const float*)d_in[13];
    const float* r2wih = (const float*)d_in[14];
    const float* r2whh = (const float*)d_in[15];
    const float* r2bih = (const float*)d_in[16];
    const float* r2bhh = (const float*)d_in[17];
    const float* fc1w  = (const float*)d_in[18];
    const float* fc1b  = (const float*)d_in[19];
    const float* fc2w  = (const float*)d_in[20];
    const float* fc2b  = (const float*)d_in[21];
    const float* fc3w  = (const float*)d_in[22];
    const float* fc3b  = (const float*)d_in[23];
    float* out = (float*)d_out;

    char* ws = (char*)d_ws;
    auto U  = [&](size_t off) { return (unsigned short*)(ws + off); };
    auto Fp = [&](size_t off) { return (float*)(ws + off); };
    (void)in_sizes; (void)n_in; (void)out_size;

    // 1) cast/pad weights + h1/h2 to bf16
    SplitArgs sa;
    sa.seg[0] = { I_w,   U(OFF_WI),   113, 128, 512 * 128 };
    sa.seg[1] = { r1wih, U(OFF_W1IH), 512, 512, 1536 * 512 };
    sa.seg[2] = { r1whh, U(OFF_W1HH), 512, 512, 1536 * 512 };
    sa.seg[3] = { r2wih, U(OFF_W2IH), 544, 576, 1536 * 576 };
    sa.seg[4] = { r2whh, U(OFF_W2HH), 512, 576, 1536 * 576 };
    sa.seg[5] = { fc1w,  U(OFF_WFC1), 544, 576, 512 * 576 };
    sa.seg[6] = { fc2w,  U(OFF_WFC2), 544, 576, 512 * 576 };
    sa.seg[7] = { fc3w,  U(OFF_WFC3), 512, 512, 512 * 512 };
    sa.seg[8] = { h1,    U(OFF_H1),   512, 512, 8192 * 512 };
    sa.seg[9] = { h2,    U(OFF_H2),   512, 576, 8192 * 576 };
    hipLaunchKernelGGL(k_split, dim3(512, 10), dim3(256), 0, stream, sa);

    // 2) C0 = [x | m_t | a1 | pad];  aux tails of X1C/X2C/X3C
    hipLaunchKernelGGL(k_build_c0, dim3(4096), dim3(256), 0, stream, xin, m_t, a1, U(OFF_C0));
    hipLaunchKernelGGL(k_fill_tail, dim3(2048), dim3(256), 0, stream, U(OFF_X1C), a2);
    hipLaunchKernelGGL(k_fill_tail, dim3(2048), dim3(256), 0, stream, U(OFF_X2C), a3);
    hipLaunchKernelGGL(k_fill_tail, dim3(2048), dim3(256), 0, stream, U(OFF_X3C), a4);

    // 3) G1: X0 = C0 @ I_w.T + I_b   (f32 + bf16)
    EpiArgs ea{};
    ea.f32_out = Fp(OFF_X0F); ea.bf_h = U(OFF_X0H); ea.out_stride = 512;
    hipLaunchKernelGGL((gemm_k<0>), dim3(128, 8), dim3(256), 0, stream,
                       U(OFF_C0), U(OFF_WI), I_b, 128, ea);

    // 4) GRU1 fused -> h1n (out), X1 (f32 + bf16 into X1C)
    GruArgs g{};
    g.hprev = h1; g.xprev = Fp(OFF_X0F);
    g.hn_out = out + 4194304; g.x_f32_out = Fp(OFF_X1F);
    g.x_bf_out = U(OFF_X1C); g.out_stride = 576;
    hipLaunchKernelGGL(gru_k, dim3(64, 8), dim3(512), 81920, stream,
                       U(OFF_X0H), U(OFF_H1), U(OFF_W1IH), U(OFF_W1HH), r1bih, r1bhh, 512, g);

    // 5) GRU2 fused -> h2n (out), X2 (bf16 into X2C)
    g = GruArgs{};
    g.hprev = h2; g.xprev = Fp(OFF_X1F);
    g.hn_out = out + 8388608; g.x_f32_out = nullptr;
    g.x_bf_out = U(OFF_X2C); g.out_stride = 576;
    hipLaunchKernelGGL(gru_k, dim3(64, 8), dim3(512), 81920, stream,
                       U(OFF_X1C), U(OFF_H2), U(OFF_W2IH), U(OFF_W2HH), r2bih, r2bhh, 576, g);

    // 6) fc1 relu -> X3C
    ea = EpiArgs{}; ea.bf_h = U(OFF_X3C); ea.out_stride = 576;
    hipLaunchKernelGGL((gemm_k<3>), dim3(128, 8), dim3(256), 0, stream,
                       U(OFF_X2C), U(OFF_WFC1), fc1b, 576, ea);
    // 7) fc2 relu -> X4
    ea = EpiArgs{}; ea.bf_h = U(OFF_X4); ea.out_stride = 512;
    hipLaunchKernelGGL((gemm_k<3>), dim3(128, 8), dim3(256), 0, stream,
                       U(OFF_X3C), U(OFF_WFC2), fc2b, 576, ea);
    // 8) fc3 logits -> d_out[0:4194304]
    ea = EpiArgs{}; ea.f32_out = out;
    hipLaunchKernelGGL((gemm_k<4>), dim3(128, 8), dim3(256), 0, stream,
                       U(OFF_X4), U(OFF_WFC3), fc3b, 512, ea);
}